// Round 5
// baseline (1205.402 us; speedup 1.0000x reference)
//
#include <hip/hip_runtime.h>
#include <stdint.h>

// SmallMLP_INR: fused 6-layer MLP (2->256->256x4->1, ReLU) over 524288 points.
// Split-bf16 MFMA (x = hi + lo, truncate split): Y = Xh*Wh + Xh*Wl + Xl*Wh in fp32.
// Operand-swapped: Yt = Wt * Xt (weights = A-frag from global, acts = B-frag in LDS).
// R5: revert to R1 geometry (MT=64, 4 waves, 64KB LDS, 2 blocks/CU) -- the
// empirical optimum of the traffic-trade family (R2/R3/R4 all regressed).
// Attack the ~45% idle matrix-pipe time directly:
//  (1) explicit 2-stage register pipeline in the ks-loop (loads for ks+1 in
//      flight under the MFMA burst of ks -- covers L2 ~300cyc / LDS ~120cyc);
//  (2) product-major MFMA order (dependent same-acc MFMAs 16 slots apart);
//  (3) v_perm_b32 epilogue packing (shrinks the serial VALU burst).

#define WIDTH 256
#define MT 64

typedef short short8 __attribute__((ext_vector_type(8)));
typedef float float4v __attribute__((ext_vector_type(4)));
typedef unsigned int uint2v __attribute__((ext_vector_type(2)));

// truncate-split f32 -> bf16 hi + bf16 lo (lo also truncated; total ~16-17 bits)
__device__ __forceinline__ void split_bf(float f, unsigned short &hi, unsigned short &lo) {
    union { float f; uint32_t u; } a; a.f = f;
    hi = (unsigned short)(a.u >> 16);
    union { uint32_t u; float f; } h; h.u = a.u & 0xffff0000u;
    union { float f; uint32_t u; } d; d.f = f - h.f;   // exact (Sterbenz)
    lo = (unsigned short)(d.u >> 16);
}

__device__ __forceinline__ float bf2f(unsigned short h) {
    union { uint32_t u; float f; } a; a.u = ((uint32_t)h) << 16; return a.f;
}

// pack hi(bf16) of two f32 into one u32 via v_perm_b32: D = {a.b2,a.b3,b.b2,b.b3}
__device__ __forceinline__ uint32_t phi2(float a, float b) {
    return __builtin_amdgcn_perm(__float_as_uint(b), __float_as_uint(a), 0x07060302u);
}
// pack lo(bf16) of two f32: residual after hi-truncation, then perm-pack
__device__ __forceinline__ uint32_t plo2(float a, float b) {
    float da = a - __uint_as_float(__float_as_uint(a) & 0xffff0000u);
    float db = b - __uint_as_float(__float_as_uint(b) & 0xffff0000u);
    return __builtin_amdgcn_perm(__float_as_uint(db), __float_as_uint(da), 0x07060302u);
}

// LDS activation addressing: X[m][n], row stride 256 ushorts, 16B-chunk index
// XOR-swizzled by (m&7) -> bank-minimal MFMA B-frag reads without padding.
__device__ __forceinline__ int xaddr(int m, int n) {
    int c = n >> 3;
    return m * 256 + (((c ^ (m & 7)) << 3) | (n & 7));
}

// Pack W2..W5 (256x256, row-major [k][n]) into MFMA fragment order:
// [l][ct(16)][ks(8)][lane(64)][j(8)], n = 16*ct + (lane&15), k = 32*ks + 8*(lane>>4) + j.
__global__ void prep_weights(const float* __restrict__ W2, const float* __restrict__ W3,
                             const float* __restrict__ W4, const float* __restrict__ W5,
                             unsigned short* __restrict__ whi, unsigned short* __restrict__ wlo) {
    int tid = blockIdx.x * 256 + threadIdx.x;   // 4*65536 total
    int l = tid >> 16;
    int e = tid & 65535;
    int j = e & 7;
    int lane = (e >> 3) & 63;
    int ks = (e >> 9) & 7;
    int ct = (e >> 12) & 15;
    int n = ct * 16 + (lane & 15);
    int k = ks * 32 + (lane >> 4) * 8 + j;
    const float* W = (l == 0) ? W2 : (l == 1) ? W3 : (l == 2) ? W4 : W5;
    float w = W[k * 256 + n];
    unsigned short hi, lo;
    split_bf(w, hi, lo);
    whi[tid] = hi;
    wlo[tid] = lo;
}

// one pipeline stage: LDS B-frags (4 pt, hi+lo) + global A-frags (4 ft, hi+lo)
__device__ __forceinline__ void load_stage(
    int l, int ks, int wv, int lane, int quad, int l16,
    const unsigned short* Xhi, const unsigned short* Xlo,
    const unsigned short* __restrict__ whi, const unsigned short* __restrict__ wlo,
    short8 xh[4], short8 xl[4], short8 wh[4], short8 wl[4])
{
    #pragma unroll
    for (int ft = 0; ft < 4; ++ft) {
        int idx = ((((l * 16) + (4 * wv + ft)) * 8 + ks) * 64 + lane) * 8;
        wh[ft] = *(const short8*)(whi + idx);
        wl[ft] = *(const short8*)(wlo + idx);
    }
    #pragma unroll
    for (int pt = 0; pt < 4; ++pt) {
        int off = xaddr(16 * pt + l16, 32 * ks + 8 * quad);
        xh[pt] = *(const short8*)(Xhi + off);
        xl[pt] = *(const short8*)(Xlo + off);
    }
}

// 48 MFMAs, product-major: dependent same-acc MFMAs are 16 issue slots apart
__device__ __forceinline__ void mfma_burst(
    const short8 xh[4], const short8 xl[4],
    const short8 wh[4], const short8 wl[4], float4v acc[4][4])
{
    __builtin_amdgcn_s_setprio(1);
    #pragma unroll
    for (int ft = 0; ft < 4; ++ft)
        #pragma unroll
        for (int pt = 0; pt < 4; ++pt)
            acc[ft][pt] = __builtin_amdgcn_mfma_f32_16x16x32_bf16(wh[ft], xh[pt], acc[ft][pt], 0, 0, 0);
    #pragma unroll
    for (int ft = 0; ft < 4; ++ft)
        #pragma unroll
        for (int pt = 0; pt < 4; ++pt)
            acc[ft][pt] = __builtin_amdgcn_mfma_f32_16x16x32_bf16(wh[ft], xl[pt], acc[ft][pt], 0, 0, 0);
    #pragma unroll
    for (int ft = 0; ft < 4; ++ft)
        #pragma unroll
        for (int pt = 0; pt < 4; ++pt)
            acc[ft][pt] = __builtin_amdgcn_mfma_f32_16x16x32_bf16(wl[ft], xh[pt], acc[ft][pt], 0, 0, 0);
    __builtin_amdgcn_s_setprio(0);
}

__global__ __launch_bounds__(256, 2) void mlp_fused(
    const float* __restrict__ coords,
    const float* __restrict__ W1, const float* __restrict__ b1,
    const float* __restrict__ b2, const float* __restrict__ b3,
    const float* __restrict__ b4, const float* __restrict__ b5,
    const float* __restrict__ W6, const float* __restrict__ b6,
    const unsigned short* __restrict__ whi, const unsigned short* __restrict__ wlo,
    float* __restrict__ out)
{
    __shared__ unsigned short Xhi[MT * 256];   // 32 KB
    __shared__ unsigned short Xlo[MT * 256];   // 32 KB  (total 64 KB -> 2 blocks/CU)

    const int tid = threadIdx.x;
    const int m0 = blockIdx.x * MT;

    // ---- layer 1: 2 -> 256 (VALU). Thread owns 4 consecutive cols nq..nq+3. ----
    {
        const int lw = tid & 63;
        const int mg = tid >> 6;
        const int nq = lw * 4;
        const float4v w0 = *(const float4v*)(W1 + nq);          // W1[0][nq..nq+3]
        const float4v w1 = *(const float4v*)(W1 + WIDTH + nq);  // W1[1][nq..nq+3]
        const float4v bb = *(const float4v*)(b1 + nq);
        for (int i = 0; i < MT / 4; ++i) {
            const int m = 4 * i + mg;
            const float c0 = coords[(m0 + m) * 2];       // wave-uniform address
            const float c1 = coords[(m0 + m) * 2 + 1];
            float v[4];
            #pragma unroll
            for (int j = 0; j < 4; ++j)
                v[j] = fmaxf(fmaf(c0, w0[j], fmaf(c1, w1[j], bb[j])), 0.0f);
            const int a = xaddr(m, nq);                  // nq&7 in {0,4}: stays in chunk
            *(uint2v*)(Xhi + a) = (uint2v){phi2(v[0], v[1]), phi2(v[2], v[3])};
            *(uint2v*)(Xlo + a) = (uint2v){plo2(v[0], v[1]), plo2(v[2], v[3])};
        }
    }
    __syncthreads();

    const int wv   = tid >> 6;     // wave 0..3 owns output features [64*wv, 64*wv+64)
    const int lane = tid & 63;
    const int quad = lane >> 4;
    const int l16  = lane & 15;

    // ---- layers 2..5: 256 -> 256 via 16x16x32 bf16 MFMA, operand-swapped,
    //      2-stage register pipeline over ks. ----
    for (int l = 0; l < 4; ++l) {
        const float* bias = (l == 0) ? b2 : (l == 1) ? b3 : (l == 2) ? b4 : b5;

        float4v acc[4][4];   // acc[ft][pt]
        #pragma unroll
        for (int ft = 0; ft < 4; ++ft)
            #pragma unroll
            for (int pt = 0; pt < 4; ++pt)
                acc[ft][pt] = (float4v){0.f, 0.f, 0.f, 0.f};

        short8 xh0[4], xl0[4], wh0[4], wl0[4];
        short8 xh1[4], xl1[4], wh1[4], wl1[4];

        load_stage(l, 0, wv, lane, quad, l16, Xhi, Xlo, whi, wlo, xh0, xl0, wh0, wl0);
        #pragma unroll
        for (int ks = 0; ks < 8; ks += 2) {
            load_stage(l, ks + 1, wv, lane, quad, l16, Xhi, Xlo, whi, wlo, xh1, xl1, wh1, wl1);
            mfma_burst(xh0, xl0, wh0, wl0, acc);
            if (ks + 2 < 8)
                load_stage(l, ks + 2, wv, lane, quad, l16, Xhi, Xlo, whi, wlo, xh0, xl0, wh0, wl0);
            mfma_burst(xh1, xl1, wh1, wl1, acc);
        }
        __syncthreads();   // all waves done reading X before overwrite

        // epilogue: D row = 4*quad + r = feature offset (4 CONSECUTIVE features
        // per thread at point m = 16*pt + l16) -> bias+ReLU+perm-pack, b64 writes.
        #pragma unroll
        for (int ft = 0; ft < 4; ++ft) {
            const int nb = 64 * wv + 16 * ft + 4 * quad;       // nb&7 in {0,4}
            const float4v bb = *(const float4v*)(bias + nb);
            #pragma unroll
            for (int pt = 0; pt < 4; ++pt) {
                const int m = 16 * pt + l16;
                float v[4];
                #pragma unroll
                for (int r = 0; r < 4; ++r)
                    v[r] = fmaxf(acc[ft][pt][r] + bb[r], 0.0f);
                const int a = xaddr(m, nb);
                *(uint2v*)(Xhi + a) = (uint2v){phi2(v[0], v[1]), phi2(v[2], v[3])};
                *(uint2v*)(Xlo + a) = (uint2v){plo2(v[0], v[1]), plo2(v[2], v[3])};
            }
        }
        __syncthreads();
    }

    // ---- layer 6: 256 -> 1 (VALU). 4 threads per point, shuffle-reduce. ----
    {
        const int m = tid >> 2;
        const int cq = tid & 3;
        float s = 0.0f;
        #pragma unroll
        for (int g = 0; g < 8; ++g) {
            int nb = cq * 64 + g * 8;
            int a = xaddr(m, nb);
            const short8 hv = *(const short8*)(Xhi + a);
            const short8 lv = *(const short8*)(Xlo + a);
            const float* wp = W6 + nb;
            #pragma unroll
            for (int j = 0; j < 8; ++j) {
                float x = bf2f((unsigned short)hv[j]) + bf2f((unsigned short)lv[j]);
                s = fmaf(x, wp[j], s);
            }
        }
        s += __shfl_xor(s, 1);
        s += __shfl_xor(s, 2);
        if (cq == 0) out[m0 + m] = s + b6[0];
    }
}

extern "C" void kernel_launch(void* const* d_in, const int* in_sizes, int n_in,
                              void* d_out, int out_size, void* d_ws, size_t ws_size,
                              hipStream_t stream) {
    const float* coords = (const float*)d_in[0];
    const float* W1 = (const float*)d_in[1];
    const float* b1 = (const float*)d_in[2];
    const float* W2 = (const float*)d_in[3];
    const float* b2 = (const float*)d_in[4];
    const float* W3 = (const float*)d_in[5];
    const float* b3 = (const float*)d_in[6];
    const float* W4 = (const float*)d_in[7];
    const float* b4 = (const float*)d_in[8];
    const float* W5 = (const float*)d_in[9];
    const float* b5 = (const float*)d_in[10];
    const float* W6 = (const float*)d_in[11];
    const float* b6 = (const float*)d_in[12];
    float* out = (float*)d_out;

    unsigned short* whi = (unsigned short*)d_ws;        // 4*65536 ushorts = 512 KB
    unsigned short* wlo = whi + 4 * 65536;              // 512 KB (ws total 1 MB)

    prep_weights<<<1024, 256, 0, stream>>>(W2, W3, W4, W5, whi, wlo);

    const int nblocks = out_size / MT;                  // 524288 / 64 = 8192
    mlp_fused<<<nblocks, 256, 0, stream>>>(coords, W1, b1, b2, b3, b4, b5,
                                           W6, b6, whi, wlo, out);
}

// Round 6
// 696.786 us; speedup vs baseline: 1.7299x; 1.7299x over previous
//
#include <hip/hip_runtime.h>
#include <stdint.h>

// SmallMLP_INR: fused 6-layer MLP (2->256->256x4->1, ReLU) over 524288 points.
// Split-bf16 MFMA (x = hi + lo, truncate split): Y = Xh*Wh + Xh*Wl + Xl*Wh in fp32.
// Operand-swapped: Yt = Wt * Xt (weights = A-frag from global, acts = B-frag in LDS).
// R6: schedule restructure, arithmetic unchanged.
//  (1) weight prefetch 1 ks ahead in NAMED statically-indexed locals (R5 lesson:
//      arrays passed to functions -> scratch -> 1.3 GB spill traffic);
//  (2) double-buffered X in LDS (128 KB): ks-loop reads buf A, epilogue writes
//      buf B -> ONE barrier per layer, wave skew absorbed, 8 waves x 32 features;
//  (3) layer 6 fused into layer 5 epilogue (dot from acc in f32, shfl+LDS reduce)
//      -> deletes L5 write-back, one barrier, and the whole L6 read pass.

#define WIDTH 256
#define MT 64

typedef short short8 __attribute__((ext_vector_type(8)));
typedef float float4v __attribute__((ext_vector_type(4)));
typedef unsigned int uint2v __attribute__((ext_vector_type(2)));

// truncate-split f32 -> bf16 hi + bf16 lo (lo also truncated; total ~16-17 bits)
__device__ __forceinline__ void split_bf(float f, unsigned short &hi, unsigned short &lo) {
    union { float f; uint32_t u; } a; a.f = f;
    hi = (unsigned short)(a.u >> 16);
    union { uint32_t u; float f; } h; h.u = a.u & 0xffff0000u;
    union { float f; uint32_t u; } d; d.f = f - h.f;   // exact (Sterbenz)
    lo = (unsigned short)(d.u >> 16);
}

// pack hi(bf16) of two f32 into one u32 via v_perm_b32: D = {a.b2,a.b3,b.b2,b.b3}
__device__ __forceinline__ uint32_t phi2(float a, float b) {
    return __builtin_amdgcn_perm(__float_as_uint(b), __float_as_uint(a), 0x07060302u);
}
// pack lo(bf16) of two f32: residual after hi-truncation, then perm-pack
__device__ __forceinline__ uint32_t plo2(float a, float b) {
    float da = a - __uint_as_float(__float_as_uint(a) & 0xffff0000u);
    float db = b - __uint_as_float(__float_as_uint(b) & 0xffff0000u);
    return __builtin_amdgcn_perm(__float_as_uint(db), __float_as_uint(da), 0x07060302u);
}

// LDS activation addressing: X[m][n], row stride 256 ushorts, 16B-chunk index
// XOR-swizzled by (m&7) -> bank-minimal MFMA B-frag reads without padding.
__device__ __forceinline__ int xaddr(int m, int n) {
    int c = n >> 3;
    return m * 256 + (((c ^ (m & 7)) << 3) | (n & 7));
}

// Pack W2..W5 (256x256, row-major [k][n]) into MFMA fragment order:
// [l][ct(16)][ks(8)][lane(64)][j(8)], n = 16*ct + (lane&15), k = 32*ks + 8*(lane>>4) + j.
__global__ void prep_weights(const float* __restrict__ W2, const float* __restrict__ W3,
                             const float* __restrict__ W4, const float* __restrict__ W5,
                             unsigned short* __restrict__ whi, unsigned short* __restrict__ wlo) {
    int tid = blockIdx.x * 256 + threadIdx.x;   // 4*65536 total
    int l = tid >> 16;
    int e = tid & 65535;
    int j = e & 7;
    int lane = (e >> 3) & 63;
    int ks = (e >> 9) & 7;
    int ct = (e >> 12) & 15;
    int n = ct * 16 + (lane & 15);
    int k = ks * 32 + (lane >> 4) * 8 + j;
    const float* W = (l == 0) ? W2 : (l == 1) ? W3 : (l == 2) ? W4 : W5;
    float w = W[k * 256 + n];
    unsigned short hi, lo;
    split_bf(w, hi, lo);
    whi[tid] = hi;
    wlo[tid] = lo;
}

// weight A-frag load: ct = 2*wv + ft (wave owns 32 consecutive features)
#define LOADW(WH, WL, L, KS)                                                   \
    do {                                                                       \
        _Pragma("unroll")                                                      \
        for (int _ft = 0; _ft < 2; ++_ft) {                                    \
            const int _idx = ((((L) * 16) + (2 * wv + _ft)) * 8 + (KS)) * 512  \
                             + lane * 8;                                       \
            WH[_ft] = *(const short8*)(whi + _idx);                            \
            WL[_ft] = *(const short8*)(wlo + _idx);                            \
        }                                                                      \
    } while (0)

__global__ __launch_bounds__(512, 2) void mlp_fused(
    const float* __restrict__ coords,
    const float* __restrict__ W1, const float* __restrict__ b1,
    const float* __restrict__ b2, const float* __restrict__ b3,
    const float* __restrict__ b4, const float* __restrict__ b5,
    const float* __restrict__ W6, const float* __restrict__ b6,
    const unsigned short* __restrict__ whi, const unsigned short* __restrict__ wlo,
    float* __restrict__ out)
{
    __shared__ unsigned short Xhi0[MT * 256];   // 32 KB  double-buffered activations
    __shared__ unsigned short Xlo0[MT * 256];   // 32 KB
    __shared__ unsigned short Xhi1[MT * 256];   // 32 KB
    __shared__ unsigned short Xlo1[MT * 256];   // 32 KB  (128 KB total -> 1 block/CU, 8 waves)

    const int tid = threadIdx.x;
    const int m0 = blockIdx.x * MT;

    const int wv   = tid >> 6;     // wave 0..7 owns output features [32*wv, 32*wv+32)
    const int lane = tid & 63;
    const int quad = lane >> 4;
    const int l16  = lane & 15;

    // issue first weight loads NOW -- L2 latency hides under layer 1 + barrier
    short8 cwh[2], cwl[2];
    LOADW(cwh, cwl, 0, 0);

    // ---- layer 1: 2 -> 256 (VALU) -> buf0. Thread owns 4 cols, 8 rounds. ----
    {
        const int nq = lane * 4;
        const float4v w0 = *(const float4v*)(W1 + nq);          // W1[0][nq..nq+3]
        const float4v w1 = *(const float4v*)(W1 + WIDTH + nq);  // W1[1][nq..nq+3]
        const float4v bb = *(const float4v*)(b1 + nq);
        #pragma unroll
        for (int i = 0; i < 8; ++i) {
            const int m = 8 * i + wv;
            const float c0 = coords[(m0 + m) * 2];       // wave-uniform address
            const float c1 = coords[(m0 + m) * 2 + 1];
            float v[4];
            #pragma unroll
            for (int j = 0; j < 4; ++j)
                v[j] = fmaxf(fmaf(c0, w0[j], fmaf(c1, w1[j], bb[j])), 0.0f);
            const int a = xaddr(m, nq);                  // nq&7 in {0,4}: stays in chunk
            *(uint2v*)(Xhi0 + a) = (uint2v){phi2(v[0], v[1]), phi2(v[2], v[3])};
            *(uint2v*)(Xlo0 + a) = (uint2v){plo2(v[0], v[1]), plo2(v[2], v[3])};
        }
    }
    __syncthreads();

    float sdot[4] = {0.f, 0.f, 0.f, 0.f};   // fused layer-6 partials

    // ---- layers 2..5: 256 -> 256 via 16x16x32 bf16 MFMA, operand-swapped.
    //      Read X[l&1], write X[1-(l&1)]; ONE barrier per layer. ----
    #pragma unroll
    for (int l = 0; l < 4; ++l) {
        const unsigned short* XH = (l & 1) ? Xhi1 : Xhi0;
        const unsigned short* XL = (l & 1) ? Xlo1 : Xlo0;
        unsigned short* YH = (l & 1) ? Xhi0 : Xhi1;
        unsigned short* YL = (l & 1) ? Xlo0 : Xlo1;
        const float* bias = (l == 0) ? b2 : (l == 1) ? b3 : (l == 2) ? b4 : b5;

        float4v acc[2][4];   // acc[ft][pt] -- 32 VGPRs
        #pragma unroll
        for (int ft = 0; ft < 2; ++ft)
            #pragma unroll
            for (int pt = 0; pt < 4; ++pt)
                acc[ft][pt] = (float4v){0.f, 0.f, 0.f, 0.f};

        #pragma unroll
        for (int ks = 0; ks < 8; ++ks) {
            // prefetch next weights (next ks, or next layer's ks=0)
            short8 nwh[2], nwl[2];
            if (ks < 7) {
                LOADW(nwh, nwl, l, ks + 1);
            } else if (l < 3) {
                LOADW(nwh, nwl, l + 1, 0);
            }
            // B-frags just-in-time from LDS: B[k][p], p = l16, k = 32*ks+8*quad+j
            short8 xh[4], xl[4];
            #pragma unroll
            for (int pt = 0; pt < 4; ++pt) {
                const int off = xaddr(16 * pt + l16, 32 * ks + 8 * quad);
                xh[pt] = *(const short8*)(XH + off);
                xl[pt] = *(const short8*)(XL + off);
            }
            __builtin_amdgcn_s_setprio(1);
            // product-major: dependent same-acc MFMAs 8 issue slots apart
            #pragma unroll
            for (int ft = 0; ft < 2; ++ft)
                #pragma unroll
                for (int pt = 0; pt < 4; ++pt)
                    acc[ft][pt] = __builtin_amdgcn_mfma_f32_16x16x32_bf16(cwh[ft], xh[pt], acc[ft][pt], 0, 0, 0);
            #pragma unroll
            for (int ft = 0; ft < 2; ++ft)
                #pragma unroll
                for (int pt = 0; pt < 4; ++pt)
                    acc[ft][pt] = __builtin_amdgcn_mfma_f32_16x16x32_bf16(cwh[ft], xl[pt], acc[ft][pt], 0, 0, 0);
            #pragma unroll
            for (int ft = 0; ft < 2; ++ft)
                #pragma unroll
                for (int pt = 0; pt < 4; ++pt)
                    acc[ft][pt] = __builtin_amdgcn_mfma_f32_16x16x32_bf16(cwl[ft], xh[pt], acc[ft][pt], 0, 0, 0);
            __builtin_amdgcn_s_setprio(0);
            // rotate (SSA renames under full unroll -- no real moves)
            cwh[0] = nwh[0]; cwh[1] = nwh[1];
            cwl[0] = nwl[0]; cwl[1] = nwl[1];
        }

        if (l < 3) {
            // epilogue: D row = 4*quad + r (4 consecutive features), col = point.
            // bias+ReLU+perm-pack, b64 writes into the OTHER buffer.
            #pragma unroll
            for (int ft = 0; ft < 2; ++ft) {
                const int nb = 32 * wv + 16 * ft + 4 * quad;   // nb&7 in {0,4}
                const float4v bb = *(const float4v*)(bias + nb);
                #pragma unroll
                for (int pt = 0; pt < 4; ++pt) {
                    const int m = 16 * pt + l16;
                    float v[4];
                    #pragma unroll
                    for (int r = 0; r < 4; ++r)
                        v[r] = fmaxf(acc[ft][pt][r] + bb[r], 0.0f);
                    const int a = xaddr(m, nb);
                    *(uint2v*)(YH + a) = (uint2v){phi2(v[0], v[1]), phi2(v[2], v[3])};
                    *(uint2v*)(YL + a) = (uint2v){plo2(v[0], v[1]), plo2(v[2], v[3])};
                }
            }
            __syncthreads();   // single barrier per layer
        } else {
            // fused layer 6: bias5 + ReLU + dot W6 straight from acc (full f32)
            #pragma unroll
            for (int ft = 0; ft < 2; ++ft) {
                const int nb = 32 * wv + 16 * ft + 4 * quad;
                const float4v bb = *(const float4v*)(bias + nb);   // b5
                const float4v w6 = *(const float4v*)(W6 + nb);
                #pragma unroll
                for (int pt = 0; pt < 4; ++pt)
                    #pragma unroll
                    for (int r = 0; r < 4; ++r) {
                        const float v = fmaxf(acc[ft][pt][r] + bb[r], 0.0f);
                        sdot[pt] = fmaf(v, w6[r], sdot[pt]);
                    }
            }
        }
    }

    // ---- layer-6 reduction: quad-shuffle, then cross-wave via 2 KB LDS ----
    {
        float* part = (float*)Xhi0;   // buf0 unused during l=3 (it read buf1)
        #pragma unroll
        for (int pt = 0; pt < 4; ++pt) {
            float s = sdot[pt];
            s += __shfl_xor(s, 16);
            s += __shfl_xor(s, 32);
            if (lane < 16) part[wv * 64 + pt * 16 + l16] = s;
        }
        __syncthreads();
        if (tid < 64) {
            float s = b6[0];
            #pragma unroll
            for (int w = 0; w < 8; ++w)
                s += part[w * 64 + tid];
            out[m0 + tid] = s;
        }
    }
}

extern "C" void kernel_launch(void* const* d_in, const int* in_sizes, int n_in,
                              void* d_out, int out_size, void* d_ws, size_t ws_size,
                              hipStream_t stream) {
    const float* coords = (const float*)d_in[0];
    const float* W1 = (const float*)d_in[1];
    const float* b1 = (const float*)d_in[2];
    const float* W2 = (const float*)d_in[3];
    const float* b2 = (const float*)d_in[4];
    const float* W3 = (const float*)d_in[5];
    const float* b3 = (const float*)d_in[6];
    const float* W4 = (const float*)d_in[7];
    const float* b4 = (const float*)d_in[8];
    const float* W5 = (const float*)d_in[9];
    const float* b5 = (const float*)d_in[10];
    const float* W6 = (const float*)d_in[11];
    const float* b6 = (const float*)d_in[12];
    float* out = (float*)d_out;

    unsigned short* whi = (unsigned short*)d_ws;        // 4*65536 ushorts = 512 KB
    unsigned short* wlo = whi + 4 * 65536;              // 512 KB (ws total 1 MB)

    prep_weights<<<1024, 256, 0, stream>>>(W2, W3, W4, W5, whi, wlo);

    const int nblocks = out_size / MT;                  // 524288 / 64 = 8192
    mlp_fused<<<nblocks, 512, 0, stream>>>(coords, W1, b1, b2, b3, b4, b5,
                                           W6, b6, whi, wlo, out);
}

// Round 7
// 640.772 us; speedup vs baseline: 1.8812x; 1.0874x over previous
//
#include <hip/hip_runtime.h>
#include <stdint.h>

// SmallMLP_INR: fused 6-layer MLP (2->256->256x4->1, ReLU) over 524288 points.
// Split-bf16 MFMA (x = hi + lo, truncate split): Y = Xh*Wh + Xh*Wl + Xl*Wh in fp32.
// Operand-swapped: Yt = Wt * Xt (weights = A-frag from global, acts = B-frag in LDS).
// R7: single-buffered X (64 KB LDS) -> 2 blocks/CU -> 4 waves/SIMD.
// Model (calibrated R6): MFMA demand = 29.8k cyc/SIMD/block at 19.4 cyc/MFMA;
// measured block time 51.6k cyc -> util 58% == measured 57%. Idle = serial
// phases with no co-resident block to overlap (1 block/CU at 128 KB).
// Keep R6's wins: 1-ks-ahead weight prefetch in named locals, fused layer 6,
// 8 waves x 32 features, perm-pack epilogue, setprio (now in its regime:
// cross-block phase diversity). Two barriers/layer (R6 proved ~free).

#define WIDTH 256
#define MT 64

typedef short short8 __attribute__((ext_vector_type(8)));
typedef float float4v __attribute__((ext_vector_type(4)));
typedef unsigned int uint2v __attribute__((ext_vector_type(2)));

// truncate-split f32 -> bf16 hi + bf16 lo (lo also truncated; total ~16-17 bits)
__device__ __forceinline__ void split_bf(float f, unsigned short &hi, unsigned short &lo) {
    union { float f; uint32_t u; } a; a.f = f;
    hi = (unsigned short)(a.u >> 16);
    union { uint32_t u; float f; } h; h.u = a.u & 0xffff0000u;
    union { float f; uint32_t u; } d; d.f = f - h.f;   // exact (Sterbenz)
    lo = (unsigned short)(d.u >> 16);
}

// pack hi(bf16) of two f32 into one u32 via v_perm_b32: D = {a.b2,a.b3,b.b2,b.b3}
__device__ __forceinline__ uint32_t phi2(float a, float b) {
    return __builtin_amdgcn_perm(__float_as_uint(b), __float_as_uint(a), 0x07060302u);
}
// pack lo(bf16) of two f32: residual after hi-truncation, then perm-pack
__device__ __forceinline__ uint32_t plo2(float a, float b) {
    float da = a - __uint_as_float(__float_as_uint(a) & 0xffff0000u);
    float db = b - __uint_as_float(__float_as_uint(b) & 0xffff0000u);
    return __builtin_amdgcn_perm(__float_as_uint(db), __float_as_uint(da), 0x07060302u);
}

// LDS activation addressing: X[m][n], row stride 256 ushorts, 16B-chunk index
// XOR-swizzled by (m&7) -> bank-minimal MFMA B-frag reads without padding.
__device__ __forceinline__ int xaddr(int m, int n) {
    int c = n >> 3;
    return m * 256 + (((c ^ (m & 7)) << 3) | (n & 7));
}

// Pack W2..W5 (256x256, row-major [k][n]) into MFMA fragment order:
// [l][ct(16)][ks(8)][lane(64)][j(8)], n = 16*ct + (lane&15), k = 32*ks + 8*(lane>>4) + j.
__global__ void prep_weights(const float* __restrict__ W2, const float* __restrict__ W3,
                             const float* __restrict__ W4, const float* __restrict__ W5,
                             unsigned short* __restrict__ whi, unsigned short* __restrict__ wlo) {
    int tid = blockIdx.x * 256 + threadIdx.x;   // 4*65536 total
    int l = tid >> 16;
    int e = tid & 65535;
    int j = e & 7;
    int lane = (e >> 3) & 63;
    int ks = (e >> 9) & 7;
    int ct = (e >> 12) & 15;
    int n = ct * 16 + (lane & 15);
    int k = ks * 32 + (lane >> 4) * 8 + j;
    const float* W = (l == 0) ? W2 : (l == 1) ? W3 : (l == 2) ? W4 : W5;
    float w = W[k * 256 + n];
    unsigned short hi, lo;
    split_bf(w, hi, lo);
    whi[tid] = hi;
    wlo[tid] = lo;
}

// weight A-frag load: ct = 2*wv + ft (wave owns 32 consecutive features)
#define LOADW(WH, WL, L, KS)                                                   \
    do {                                                                       \
        _Pragma("unroll")                                                      \
        for (int _ft = 0; _ft < 2; ++_ft) {                                    \
            const int _idx = ((((L) * 16) + (2 * wv + _ft)) * 8 + (KS)) * 512  \
                             + lane * 8;                                       \
            WH[_ft] = *(const short8*)(whi + _idx);                            \
            WL[_ft] = *(const short8*)(wlo + _idx);                            \
        }                                                                      \
    } while (0)

__global__ __launch_bounds__(512, 4) void mlp_fused(
    const float* __restrict__ coords,
    const float* __restrict__ W1, const float* __restrict__ b1,
    const float* __restrict__ b2, const float* __restrict__ b3,
    const float* __restrict__ b4, const float* __restrict__ b5,
    const float* __restrict__ W6, const float* __restrict__ b6,
    const unsigned short* __restrict__ whi, const unsigned short* __restrict__ wlo,
    float* __restrict__ out)
{
    __shared__ unsigned short Xhi[MT * 256];   // 32 KB
    __shared__ unsigned short Xlo[MT * 256];   // 32 KB  (total 64 KB -> 2 blocks/CU)

    const int tid = threadIdx.x;
    const int m0 = blockIdx.x * MT;

    const int wv   = tid >> 6;     // wave 0..7 owns output features [32*wv, 32*wv+32)
    const int lane = tid & 63;
    const int quad = lane >> 4;
    const int l16  = lane & 15;

    // issue first weight loads NOW -- L2 latency hides under layer 1 + barrier
    short8 cwh[2], cwl[2];
    LOADW(cwh, cwl, 0, 0);

    // ---- layer 1: 2 -> 256 (VALU) -> X. Thread owns 4 cols, 8 rounds. ----
    {
        const int nq = lane * 4;
        const float4v w0 = *(const float4v*)(W1 + nq);          // W1[0][nq..nq+3]
        const float4v w1 = *(const float4v*)(W1 + WIDTH + nq);  // W1[1][nq..nq+3]
        const float4v bb = *(const float4v*)(b1 + nq);
        #pragma unroll
        for (int i = 0; i < 8; ++i) {
            const int m = 8 * i + wv;
            const float c0 = coords[(m0 + m) * 2];       // wave-uniform address
            const float c1 = coords[(m0 + m) * 2 + 1];
            float v[4];
            #pragma unroll
            for (int j = 0; j < 4; ++j)
                v[j] = fmaxf(fmaf(c0, w0[j], fmaf(c1, w1[j], bb[j])), 0.0f);
            const int a = xaddr(m, nq);                  // nq&7 in {0,4}: stays in chunk
            *(uint2v*)(Xhi + a) = (uint2v){phi2(v[0], v[1]), phi2(v[2], v[3])};
            *(uint2v*)(Xlo + a) = (uint2v){plo2(v[0], v[1]), plo2(v[2], v[3])};
        }
    }
    __syncthreads();

    float sdot[4] = {0.f, 0.f, 0.f, 0.f};   // fused layer-6 partials

    // ---- layers 2..5: 256 -> 256 via 16x16x32 bf16 MFMA, operand-swapped.
    //      Single X buffer: barrier after reads, barrier after writes. ----
    #pragma unroll
    for (int l = 0; l < 4; ++l) {
        const float* bias = (l == 0) ? b2 : (l == 1) ? b3 : (l == 2) ? b4 : b5;

        float4v acc[2][4];   // acc[ft][pt] -- 32 VGPRs
        #pragma unroll
        for (int ft = 0; ft < 2; ++ft)
            #pragma unroll
            for (int pt = 0; pt < 4; ++pt)
                acc[ft][pt] = (float4v){0.f, 0.f, 0.f, 0.f};

        #pragma unroll
        for (int ks = 0; ks < 8; ++ks) {
            // prefetch next weights (next ks, or next layer's ks=0)
            short8 nwh[2], nwl[2];
            if (ks < 7) {
                LOADW(nwh, nwl, l, ks + 1);
            } else if (l < 3) {
                LOADW(nwh, nwl, l + 1, 0);
            }
            // B-frags just-in-time from LDS: B[k][p], p = l16, k = 32*ks+8*quad+j
            short8 xh[4], xl[4];
            #pragma unroll
            for (int pt = 0; pt < 4; ++pt) {
                const int off = xaddr(16 * pt + l16, 32 * ks + 8 * quad);
                xh[pt] = *(const short8*)(Xhi + off);
                xl[pt] = *(const short8*)(Xlo + off);
            }
            __builtin_amdgcn_s_setprio(1);
            // product-major: dependent same-acc MFMAs 8 issue slots apart
            #pragma unroll
            for (int ft = 0; ft < 2; ++ft)
                #pragma unroll
                for (int pt = 0; pt < 4; ++pt)
                    acc[ft][pt] = __builtin_amdgcn_mfma_f32_16x16x32_bf16(cwh[ft], xh[pt], acc[ft][pt], 0, 0, 0);
            #pragma unroll
            for (int ft = 0; ft < 2; ++ft)
                #pragma unroll
                for (int pt = 0; pt < 4; ++pt)
                    acc[ft][pt] = __builtin_amdgcn_mfma_f32_16x16x32_bf16(cwh[ft], xl[pt], acc[ft][pt], 0, 0, 0);
            #pragma unroll
            for (int ft = 0; ft < 2; ++ft)
                #pragma unroll
                for (int pt = 0; pt < 4; ++pt)
                    acc[ft][pt] = __builtin_amdgcn_mfma_f32_16x16x32_bf16(cwl[ft], xh[pt], acc[ft][pt], 0, 0, 0);
            __builtin_amdgcn_s_setprio(0);
            // rotate (SSA renames under full unroll -- no real moves)
            cwh[0] = nwh[0]; cwh[1] = nwh[1];
            cwl[0] = nwl[0]; cwl[1] = nwl[1];
        }
        __syncthreads();   // all waves done READING X before overwrite

        if (l < 3) {
            // epilogue: D row = 4*quad + r (4 consecutive features), col = point.
            // bias+ReLU+perm-pack, b64 writes back into X.
            #pragma unroll
            for (int ft = 0; ft < 2; ++ft) {
                const int nb = 32 * wv + 16 * ft + 4 * quad;   // nb&7 in {0,4}
                const float4v bb = *(const float4v*)(bias + nb);
                #pragma unroll
                for (int pt = 0; pt < 4; ++pt) {
                    const int m = 16 * pt + l16;
                    float v[4];
                    #pragma unroll
                    for (int r = 0; r < 4; ++r)
                        v[r] = fmaxf(acc[ft][pt][r] + bb[r], 0.0f);
                    const int a = xaddr(m, nb);
                    *(uint2v*)(Xhi + a) = (uint2v){phi2(v[0], v[1]), phi2(v[2], v[3])};
                    *(uint2v*)(Xlo + a) = (uint2v){plo2(v[0], v[1]), plo2(v[2], v[3])};
                }
            }
            __syncthreads();   // writes visible before next layer's reads
        } else {
            // fused layer 6: bias5 + ReLU + dot W6 straight from acc (full f32)
            #pragma unroll
            for (int ft = 0; ft < 2; ++ft) {
                const int nb = 32 * wv + 16 * ft + 4 * quad;
                const float4v bb = *(const float4v*)(bias + nb);   // b5
                const float4v w6 = *(const float4v*)(W6 + nb);
                #pragma unroll
                for (int pt = 0; pt < 4; ++pt)
                    #pragma unroll
                    for (int r = 0; r < 4; ++r) {
                        const float v = fmaxf(acc[ft][pt][r] + bb[r], 0.0f);
                        sdot[pt] = fmaf(v, w6[r], sdot[pt]);
                    }
            }
        }
    }

    // ---- layer-6 reduction: quad-shuffle, then cross-wave via 2 KB LDS ----
    // (post-ks-loop barrier above guarantees all waves are done reading X)
    {
        float* part = (float*)Xhi;
        #pragma unroll
        for (int pt = 0; pt < 4; ++pt) {
            float s = sdot[pt];
            s += __shfl_xor(s, 16);
            s += __shfl_xor(s, 32);
            if (lane < 16) part[wv * 64 + pt * 16 + l16] = s;
        }
        __syncthreads();
        if (tid < 64) {
            float s = b6[0];
            #pragma unroll
            for (int w = 0; w < 8; ++w)
                s += part[w * 64 + tid];
            out[m0 + tid] = s;
        }
    }
}

extern "C" void kernel_launch(void* const* d_in, const int* in_sizes, int n_in,
                              void* d_out, int out_size, void* d_ws, size_t ws_size,
                              hipStream_t stream) {
    const float* coords = (const float*)d_in[0];
    const float* W1 = (const float*)d_in[1];
    const float* b1 = (const float*)d_in[2];
    const float* W2 = (const float*)d_in[3];
    const float* b2 = (const float*)d_in[4];
    const float* W3 = (const float*)d_in[5];
    const float* b3 = (const float*)d_in[6];
    const float* W4 = (const float*)d_in[7];
    const float* b4 = (const float*)d_in[8];
    const float* W5 = (const float*)d_in[9];
    const float* b5 = (const float*)d_in[10];
    const float* W6 = (const float*)d_in[11];
    const float* b6 = (const float*)d_in[12];
    float* out = (float*)d_out;

    unsigned short* whi = (unsigned short*)d_ws;        // 4*65536 ushorts = 512 KB
    unsigned short* wlo = whi + 4 * 65536;              // 512 KB (ws total 1 MB)

    prep_weights<<<1024, 256, 0, stream>>>(W2, W3, W4, W5, whi, wlo);

    const int nblocks = out_size / MT;                  // 524288 / 64 = 8192
    mlp_fused<<<nblocks, 512, 0, stream>>>(coords, W1, b1, b2, b3, b4, b5,
                                           W6, b6, whi, wlo, out);
}